// Round 3
// baseline (224.708 us; speedup 1.0000x reference)
//
#include <hip/hip_runtime.h>
#include <hip/hip_bf16.h>
#include <math.h>

// ---------------------------------------------------------------------------
// SE3 warping field: nerf_encode -> 6-layer MLP (skip@4) -> heads -> se3 exp
// Round 3: whole-layer W register preload + cross-layer W/bias prefetch with
// raw s_barrier (no vmcnt drain), vectorized encode stores.
// ---------------------------------------------------------------------------

typedef __bf16 bf16x8 __attribute__((ext_vector_type(8)));
typedef float  f32x4  __attribute__((ext_vector_type(4)));

#define NROWS 524288
#define BROWS 128

// packed-weight offsets in bf16 elements: [frag f][kstep s][lane][j]
// frag f = out-col group (rows m = 16f + (lane&15)), k = 32s + 8*(lane>>4) + j
#define P0 0        // L0: K=64  (53 padded)
#define P1 8192     // L1: K=128
#define P2 24576
#define P3 40960
#define P4 57344    // L4: K=192 (53+pad11 | 128)
#define P5 81920
#define PH 98304    // head: m 0..2=Wv rows, 3..5=Wr rows, rest 0
#define PTOT 100352

// LDS byte offsets
#define X0_OFF 0        // [128][64 bf16]  stride 128B (encoded input; dead after L4)
#define XA_OFF 16384    // [128][128 bf16] stride 256B (in-place activations)
#define SC_OFF 0        // screw [128][8 f32] (aliases X0; written at head phase)
#define LDS_SZ 49152

// ---------------------------------------------------------------------------
template<int KS, int FAN>
__device__ __forceinline__ float pack_val(const float* __restrict__ W, int idx)
{
    int f  = idx / (KS * 512);          // compile-time divisor
    int r2 = idx % (KS * 512);
    int s  = r2 >> 9, r3 = r2 & 511, ln = r3 >> 3, j = r3 & 7;
    int col = f * 16 + (ln & 15);
    int k   = s * 32 + (ln >> 4) * 8 + j;
    if (FAN == 128) return W[col * 128 + k];
    if (FAN == 53)  return (k < 53) ? W[col * 53 + k] : 0.f;
    // FAN == 181 padded to 192: [0..52]=inp, [53..63]=0, [64..191]=x
    if (k < 53)  return W[col * 181 + k];
    if (k < 64)  return 0.f;
    return W[col * 181 + (k - 11)];
}

__global__ void pack_w(const float* __restrict__ W0, const float* __restrict__ W1,
                       const float* __restrict__ W2, const float* __restrict__ W3,
                       const float* __restrict__ W4, const float* __restrict__ W5,
                       const float* __restrict__ Wr, const float* __restrict__ Wv,
                       __bf16* __restrict__ pk)
{
    int e = blockIdx.x * 256 + threadIdx.x;
    if (e >= PTOT) return;
    float val;
    if (e >= PH) {                                   // head fragment
        int rem = e - PH;
        int s = rem >> 9, r3 = rem & 511, ln = r3 >> 3, j = r3 & 7;
        int col = ln & 15;
        int k = s * 32 + (ln >> 4) * 8 + j;
        if (col < 3)      val = Wv[col * 128 + k];        // v = feat@Wv^T
        else if (col < 6) val = Wr[(col - 3) * 128 + k];  // r = feat@Wr^T
        else              val = 0.f;
    }
    else if (e < P1) val = pack_val<2, 53 >(W0, e - P0);
    else if (e < P2) val = pack_val<4, 128>(W1, e - P1);
    else if (e < P3) val = pack_val<4, 128>(W2, e - P2);
    else if (e < P4) val = pack_val<4, 128>(W3, e - P3);
    else if (e < P5) val = pack_val<6, 181>(W4, e - P4);
    else             val = pack_val<4, 128>(W5, e - P5);
    pk[e] = (__bf16)val;
}

// ---------------------------------------------------------------------------
__device__ __forceinline__ unsigned pack_bf16_2(float a, float b) {
    union { __bf16 h; unsigned short u; } x, y;
    x.h = (__bf16)a; y.h = (__bf16)b;
    return ((unsigned)y.u << 16) | (unsigned)x.u;
}

// One MLP layer, swapped scheme (Y^T = W * X^T). Wave (mfG,nfG) of 2x2:
//   owns out-cols m in [64*mfG, 64*mfG+64), batch rows [64*nfG, 64*nfG+64).
// W fragments for the layer are fully register-resident (preloaded by the
// previous layer's prefetch phase, or in-loop for KS=6 steps 4..5).
template<int KS, int SPLITS, int KSN>
__device__ __forceinline__ void mlp_layer(unsigned char* smem,
    bf16x8 (&W)[4][4], f32x4 (&Bias)[4],
    const __bf16* __restrict__ pkCur, const __bf16* __restrict__ pkNext,
    const float* __restrict__ biasNext,
    int inOff, int inStride, int outOff,
    int lane, int cl, int gp, int mfG, int nfG)
{
    f32x4 acc[4][4];
    #pragma unroll
    for (int mf = 0; mf < 4; mf++)
        #pragma unroll
        for (int nf = 0; nf < 4; nf++) acc[mf][nf] = Bias[mf];

    bf16x8 Bf[2][4];
    auto loadB = [&](bf16x8* dst, int s) {
        int base, stride, k0;
        if (s < SPLITS) { base = X0_OFF; stride = 128;      k0 = s * 32; }
        else            { base = inOff;  stride = inStride; k0 = (s - SPLITS) * 32; }
        int bc = 2 * k0 + 16 * gp;
        #pragma unroll
        for (int nf = 0; nf < 4; nf++) {
            int row = nfG * 64 + nf * 16 + cl;
            dst[nf] = *(const bf16x8*)(smem + base + row * stride
                                       + (bc ^ ((row & 7) << 4)));
        }
    };

    loadB(Bf[0], 0);
    #pragma unroll
    for (int s = 0; s < KS; s++) {
        if (s + 1 < KS) loadB(Bf[(s + 1) & 1], s + 1);
        #pragma unroll
        for (int mf = 0; mf < 4; mf++)
            #pragma unroll
            for (int nf = 0; nf < 4; nf++)
                acc[mf][nf] = __builtin_amdgcn_mfma_f32_16x16x32_bf16(
                    W[s & 3][mf], Bf[s & 1][nf], acc[mf][nf], 0, 0, 0);
        if constexpr (KS > 4) {
            if (s + 4 < KS) {       // in-loop W load for steps 4..KS-1
                const bf16x8* pC = (const bf16x8*)pkCur;
                #pragma unroll
                for (int mf = 0; mf < 4; mf++)
                    W[(s + 4) & 3][mf] = pC[((mfG * 4 + mf) * KS + (s + 4)) * 64 + lane];
            }
        }
    }

    __syncthreads();   // barrier1: all reads of in-place buffer complete
                       // (vm/lgkm naturally drained: everything consumed)

    // ---- prefetch next layer's W + bias while stores run; loads stay in
    // ---- flight across the raw barrier below.
    if constexpr (KSN > 0) {
        constexpr int PF = (KSN > 4) ? 4 : KSN;
        const bf16x8* pN = (const bf16x8*)pkNext;
        #pragma unroll
        for (int s = 0; s < PF; s++)
            #pragma unroll
            for (int mf = 0; mf < 4; mf++)
                W[s][mf] = pN[((mfG * 4 + mf) * KSN + s) * 64 + lane];
        #pragma unroll
        for (int mf = 0; mf < 4; mf++)
            Bias[mf] = *(const f32x4*)(biasNext + mfG * 64 + mf * 16 + gp * 4);
    }

    // ---- ReLU + pack + in-place store (D: col=lane&15, row=(lane>>4)*4+reg)
    #pragma unroll
    for (int mf = 0; mf < 4; mf++)
        #pragma unroll
        for (int nf = 0; nf < 4; nf++) {
            int row = nfG * 64 + nf * 16 + cl;
            int bc  = 128 * mfG + 32 * mf + 8 * gp;
            f32x4 a = acc[mf][nf];
            uint2 w;
            w.x = pack_bf16_2(fmaxf(a[0], 0.f), fmaxf(a[1], 0.f));
            w.y = pack_bf16_2(fmaxf(a[2], 0.f), fmaxf(a[3], 0.f));
            *(uint2*)(smem + outOff + row * 256 + (bc ^ ((row & 7) << 4))) = w;
        }

    // barrier2: drain LDS writes only; W/bias prefetch stays outstanding.
    asm volatile("s_waitcnt lgkmcnt(0)" ::: "memory");
    __builtin_amdgcn_s_barrier();
    asm volatile("" ::: "memory");
}

// ---------------------------------------------------------------------------
__global__ __launch_bounds__(256, 3)
void se3_fused(const float* __restrict__ pos, const float* __restrict__ dir,
               const float* __restrict__ wcode,
               const float* __restrict__ b0, const float* __restrict__ b1,
               const float* __restrict__ b2, const float* __restrict__ b3,
               const float* __restrict__ b4, const float* __restrict__ b5,
               const float* __restrict__ br, const float* __restrict__ bv,
               const __bf16* __restrict__ pk,
               float* __restrict__ out)
{
    __shared__ unsigned char smem[LDS_SZ];
    const int tid  = threadIdx.x;
    const int lane = tid & 63;
    const int cl   = lane & 15;
    const int gp   = lane >> 4;
    const int wid  = tid >> 6;
    const int mfG  = wid & 1;
    const int nfG  = wid >> 1;
    const int r0   = blockIdx.x * BROWS;

    // ---- issue L0 weights + bias immediately (latency hidden under encode)
    bf16x8 W[4][4];
    f32x4  Bias[4];
    {
        const bf16x8* p0v = (const bf16x8*)(pk + P0);
        #pragma unroll
        for (int s = 0; s < 2; s++)
            #pragma unroll
            for (int mf = 0; mf < 4; mf++)
                W[s][mf] = p0v[((mfG * 4 + mf) * 2 + s) * 64 + lane];
        #pragma unroll
        for (int mf = 0; mf < 4; mf++)
            Bias[mf] = *(const f32x4*)(b0 + mfG * 64 + mf * 16 + gp * 4);
    }

    // ---------------- encode: X0[row][64] = [sin21 | cos21 | p3 | wc8 | 0*11]
    // thread (row, h): h=0 -> cols 0..31, h=1 -> cols 32..63; 4 x b128 stores.
    {
        int row = tid >> 1, h = tid & 1;
        int g = r0 + row;
        float p0 = pos[g*3+0], p1 = pos[g*3+1], p2 = pos[g*3+2];
        float vals[32];
        if (h == 0) {
            #pragma unroll
            for (int j = 0; j < 21; j++) {          // sin cols 0..20
                float p = (j < 7) ? p0 : (j < 14 ? p1 : p2);
                float t = p * (float)(1 << (j % 7));
                t -= floorf(t);
                vals[j] = __sinf(6.283185307179586f * t);
            }
            #pragma unroll
            for (int j = 21; j < 32; j++) {         // cos idx 0..10 (cols 21..31)
                int idx = j - 21;
                float p = (idx < 7) ? p0 : (idx < 14 ? p1 : p2);
                float t = p * (float)(1 << (idx % 7));
                t -= floorf(t);
                vals[j] = __cosf(6.283185307179586f * t);
            }
        } else {
            #pragma unroll
            for (int j = 0; j < 10; j++) {          // cos idx 11..20 (cols 32..41)
                int idx = 11 + j;
                float p = (idx < 14) ? p1 : p2;
                float t = p * (float)(1 << (idx % 7));
                t -= floorf(t);
                vals[j] = __cosf(6.283185307179586f * t);
            }
            vals[10] = p0; vals[11] = p1; vals[12] = p2;   // cols 42..44
            const float4* wc4 = (const float4*)(wcode + (size_t)g * 8);
            float4 wa = wc4[0], wb = wc4[1];
            vals[13] = wa.x; vals[14] = wa.y; vals[15] = wa.z; vals[16] = wa.w;
            vals[17] = wb.x; vals[18] = wb.y; vals[19] = wb.z; vals[20] = wb.w;
            #pragma unroll
            for (int j = 21; j < 32; j++) vals[j] = 0.f;   // cols 53..63
        }
        unsigned pkd[16];
        #pragma unroll
        for (int i = 0; i < 16; i++) pkd[i] = pack_bf16_2(vals[2*i], vals[2*i+1]);
        unsigned char* base = smem + X0_OFF + row * 128;
        int sw = (row & 7) << 4;
        #pragma unroll
        for (int c = 0; c < 4; c++) {
            uint4 w; w.x = pkd[4*c]; w.y = pkd[4*c+1]; w.z = pkd[4*c+2]; w.w = pkd[4*c+3];
            *(uint4*)(base + ((64 * h + 16 * c) ^ sw)) = w;
        }
    }
    __syncthreads();

    // ---------------- MLP stem (in-place single buffer XA) ------------------
    mlp_layer<2,0,4>(smem, W, Bias, pk+P0, pk+P1, b1, X0_OFF, 128, XA_OFF, lane, cl, gp, mfG, nfG);
    mlp_layer<4,0,4>(smem, W, Bias, pk+P1, pk+P2, b2, XA_OFF, 256, XA_OFF, lane, cl, gp, mfG, nfG);
    mlp_layer<4,0,4>(smem, W, Bias, pk+P2, pk+P3, b3, XA_OFF, 256, XA_OFF, lane, cl, gp, mfG, nfG);
    mlp_layer<4,0,6>(smem, W, Bias, pk+P3, pk+P4, b4, XA_OFF, 256, XA_OFF, lane, cl, gp, mfG, nfG);
    mlp_layer<6,2,4>(smem, W, Bias, pk+P4, pk+P5, b5, XA_OFF, 256, XA_OFF, lane, cl, gp, mfG, nfG); // skip
    mlp_layer<4,0,0>(smem, W, Bias, pk+P5, nullptr, nullptr, XA_OFF, 256, XA_OFF, lane, cl, gp, mfG, nfG);

    // ---------------- heads: screw = [v(3) | r(3)] (mfG==0 waves only) ------
    if (mfG == 0) {
        const bf16x8* pW = (const bf16x8*)(pk + PH);
        bf16x8 Wh[4];
        #pragma unroll
        for (int s = 0; s < 4; s++) Wh[s] = pW[s * 64 + lane];
        f32x4 hb;
        #pragma unroll
        for (int r = 0; r < 4; r++) {
            int m = gp * 4 + r;
            hb[r] = (m < 3) ? bv[m] : ((m < 6) ? br[m - 3] : 0.f);
        }
        f32x4 hacc[4];
        #pragma unroll
        for (int nf = 0; nf < 4; nf++) hacc[nf] = hb;
        #pragma unroll
        for (int s = 0; s < 4; s++) {
            int bc = 64 * s + 16 * gp;
            #pragma unroll
            for (int nf = 0; nf < 4; nf++) {
                int row = nfG * 64 + nf * 16 + cl;
                bf16x8 B = *(const bf16x8*)(smem + XA_OFF + row * 256
                                            + (bc ^ ((row & 7) << 4)));
                hacc[nf] = __builtin_amdgcn_mfma_f32_16x16x32_bf16(Wh[s], B, hacc[nf], 0, 0, 0);
            }
        }
        // screw store: lane(cl,gp) holds m=4gp+r for batch row nfG*64+nf*16+cl
        #pragma unroll
        for (int nf = 0; nf < 4; nf++) {
            int row = nfG * 64 + nf * 16 + cl;
            if (gp == 0) {
                *(f32x4*)(smem + SC_OFF + row * 32) = hacc[nf];         // m 0..3
            } else if (gp == 1) {
                *(float*)(smem + SC_OFF + row * 32 + 16) = hacc[nf][0]; // m 4
                *(float*)(smem + SC_OFF + row * 32 + 20) = hacc[nf][1]; // m 5
            }
        }
    }
    __syncthreads();

    // ---------------- se3 exp map epilogue (fp32, 1 thread per row) ---------
    if (tid < BROWS) {
        int row = tid, g = r0 + row;
        const float* sc = (const float*)(smem + SC_OFF + row * 32);
        float v0 = sc[0], v1 = sc[1], v2 = sc[2];
        float wx = sc[3], wy = sc[4], wz = sc[5];
        float ang2 = wx*wx + wy*wy + wz*wz;
        ang2 = fmaxf(ang2, 1e-4f);               // jnp.clip(.., eps)
        float ang = sqrtf(ang2);
        float sn = __sinf(ang), cs = __cosf(ang);
        float f1 = sn / ang;
        float f2 = (1.f - cs) / ang2;
        float f3 = (ang - sn) / (ang * ang2);
        float K[3][3] = {{0.f,  wz, -wy}, {-wz, 0.f,  wx}, { wy, -wx, 0.f}};
        float KK[3][3];
        #pragma unroll
        for (int i = 0; i < 3; i++)
            #pragma unroll
            for (int j = 0; j < 3; j++)
                KK[i][j] = K[i][0]*K[0][j] + K[i][1]*K[1][j] + K[i][2]*K[2][j];
        float R[3][3], V[3][3];
        #pragma unroll
        for (int i = 0; i < 3; i++)
            #pragma unroll
            for (int j = 0; j < 3; j++) {
                float id = (i == j) ? 1.f : 0.f;
                R[i][j] = id + f1 * K[i][j] + f2 * KK[i][j];
                V[i][j] = id + f2 * K[i][j] + f3 * KK[i][j];
            }
        float T0 = V[0][0]*v0 + V[0][1]*v1 + V[0][2]*v2;
        float T1 = V[1][0]*v0 + V[1][1]*v1 + V[1][2]*v2;
        float T2 = V[2][0]*v0 + V[2][1]*v1 + V[2][2]*v2;
        float px = pos[g*3+0], py = pos[g*3+1], pz = pos[g*3+2];
        float dx = dir[g*3+0], dy = dir[g*3+1], dz = dir[g*3+2];
        // M_rot = R^T : wp[i] = sum_j R[j][i]*p[j] + T[i]
        float wpx = R[0][0]*px + R[1][0]*py + R[2][0]*pz + T0;
        float wpy = R[0][1]*px + R[1][1]*py + R[2][1]*pz + T1;
        float wpz = R[0][2]*px + R[1][2]*py + R[2][2]*pz + T2;
        float wdx = R[0][0]*dx + R[1][0]*dy + R[2][0]*dz;
        float wdy = R[0][1]*dx + R[1][1]*dy + R[2][1]*dz;
        float wdz = R[0][2]*dx + R[1][2]*dy + R[2][2]*dz;
        wpx = (wpx != wpx) ? px : wpx;
        wpy = (wpy != wpy) ? py : wpy;
        wpz = (wpz != wpz) ? pz : wpz;
        wdx = (wdx != wdx) ? dx : wdx;
        wdy = (wdy != wdy) ? dy : wdy;
        wdz = (wdz != wdz) ? dz : wdz;
        out[g*3+0] = wpx; out[g*3+1] = wpy; out[g*3+2] = wpz;
        float* o2 = out + (size_t)NROWS * 3;
        o2[g*3+0] = wdx; o2[g*3+1] = wdy; o2[g*3+2] = wdz;
    }
}

// ---------------------------------------------------------------------------
extern "C" void kernel_launch(void* const* d_in, const int* in_sizes, int n_in,
                              void* d_out, int out_size, void* d_ws, size_t ws_size,
                              hipStream_t stream)
{
    const float* pos = (const float*)d_in[0];
    const float* dir = (const float*)d_in[1];
    const float* wc  = (const float*)d_in[2];
    const float* W0 = (const float*)d_in[3];  const float* b0 = (const float*)d_in[4];
    const float* W1 = (const float*)d_in[5];  const float* b1 = (const float*)d_in[6];
    const float* W2 = (const float*)d_in[7];  const float* b2 = (const float*)d_in[8];
    const float* W3 = (const float*)d_in[9];  const float* b3 = (const float*)d_in[10];
    const float* W4 = (const float*)d_in[11]; const float* b4 = (const float*)d_in[12];
    const float* W5 = (const float*)d_in[13]; const float* b5 = (const float*)d_in[14];
    const float* Wr = (const float*)d_in[15]; const float* br = (const float*)d_in[16];
    const float* Wv = (const float*)d_in[17]; const float* bv = (const float*)d_in[18];
    __bf16* pk = (__bf16*)d_ws;
    float* out = (float*)d_out;

    pack_w<<<(PTOT + 255) / 256, 256, 0, stream>>>(W0, W1, W2, W3, W4, W5, Wr, Wv, pk);
    se3_fused<<<NROWS / BROWS, 256, 0, stream>>>(pos, dir, wc,
                                                 b0, b1, b2, b3, b4, b5,
                                                 br, bv, pk, out);
}